// Round 1
// baseline (285.924 us; speedup 1.0000x reference)
//
#include <hip/hip_runtime.h>
#include <math.h>

#define TLEN 512
#define NCH  128
#define KP   4
#define PMAXV 64
#define CMAXV 32
#define MINP 16
#define NSEQ 4096   // B*N = 32*128
#define OUTG ((size_t)NSEQ * KP * CMAXV * PMAXV)   // 33,554,432

// pad-per-8 for 16B (double2) LDS elements: breaks power-of-2 bank strides
#define PAD8(i) ((i) + ((i) >> 3))
#define ZP   290            // >= PAD8(255)+1 = 287
#define SEQP 520            // padded f32 sequence row

typedef float nfloat4 __attribute__((ext_vector_type(4)));

// ---------------------------------------------------------------------------
// R12: two-kernel split.
//  - Kernel 1 (unchanged FP64 FFT + top-4, high VGPR) writes kamp + int4 bin
//    table to d_ws (64 KB).
//  - Kernel 2 (lean f32 gather/store, __launch_bounds__(512,8) -> VGPR<=64,
//    32 waves/CU) re-stages rows from x (L3-resident) and streams g/m with
//    nontemporal stores. Mask stores issued BEFORE the staging barrier (they
//    don't depend on x), hiding load latency.
//  Rationale: single-kernel store phase ran at ~2.8 TB/s (98 us) because the
//  FFT's FP64 register pressure capped occupancy at ~16 waves/CU and stores
//  only started after the serial FFT. Store floor is ~43 us at 6.35 TB/s
//  (proven by the harness fill kernel).
// ---------------------------------------------------------------------------

// One block = 4 sequences, one WAVE per sequence; one block barrier total.
// Real-input 512-pt FFT via 256-pt complex FFT + register untangle.
__global__ __launch_bounds__(256) void fft_topk_kernel(
    const float* __restrict__ x,
    float* __restrict__ out_a,
    int4* __restrict__ bins)
{
    const int tid  = threadIdx.x;
    const int lane = tid & 63;
    const int w    = tid >> 6;          // wave id = local sequence id
    const int s0   = blockIdx.x << 2;   // first sequence of this block
    const int b    = s0 >> 7;           // all 4 seqs share b (4 | 128)
    const int n0   = s0 & (NCH - 1);    // multiple of 4

    __shared__ float   seqf[4 * SEQP];
    __shared__ double2 Z[4 * ZP];
    __shared__ double2 W[256];          // W_512^j, j=0..255

    // ---- cooperative load + in-block twiddle table ----
    {
        const int col = tid & 3;
        const int t0  = tid >> 2;       // 0..63
        const float* base = x + (size_t)b * TLEN * NCH + n0 + col;
        #pragma unroll
        for (int it = 0; it < 8; ++it) {
            const int t = t0 + 64 * it;
            seqf[col * SEQP + t] = base[(size_t)t * NCH];
        }
        double ang = -6.283185307179586476925286766559 * (double)tid / (double)TLEN;
        double sv, cv;
        sincos(ang, &sv, &cv);
        W[tid] = make_double2(cv, sv);
    }
    __syncthreads();                    // the ONLY block barrier

    float*   sf = seqf + w * SEQP;
    double2* Zw = Z + w * ZP;

    // ---- pack z[t]=x[2t]+i*x[2t+1], bit-reverse (8-bit), 4 pts/lane ----
    #pragma unroll
    for (int u = 0; u < 4; ++u) {
        const int i = lane + 64 * u;
        const int r = (int)(__brev((unsigned)i) >> 24);   // 8-bit reverse
        const float2 p = ((const float2*)sf)[r];          // x[2r], x[2r+1]
        Zw[PAD8(i)] = make_double2((double)p.x, (double)p.y);
    }
    __builtin_amdgcn_wave_barrier();

    // ---- 8 radix-2 DIT stages over 256 complex pts (2 butterflies/lane) ----
    for (int st = 1; st <= 8; ++st) {
        const int half = 1 << (st - 1);
        #pragma unroll
        for (int u = 0; u < 2; ++u) {
            const int j   = lane + 64 * u;                // butterfly id 0..127
            const int pos = j & (half - 1);
            const int i1  = ((j >> (st - 1)) << st) + pos;
            const int i2  = i1 + half;
            // W_256^(pos<<(8-st)) == W_512^(pos<<(9-st))
            const double2 wv = W[pos << (9 - st)];
            const double2 a  = Zw[PAD8(i1)];
            const double2 c  = Zw[PAD8(i2)];
            const double tr = wv.x * c.x - wv.y * c.y;
            const double ti = wv.x * c.y + wv.y * c.x;
            Zw[PAD8(i1)] = make_double2(a.x + tr, a.y + ti);
            Zw[PAD8(i2)] = make_double2(a.x - tr, a.y - ti);
        }
        __builtin_amdgcn_wave_barrier();
    }

    // ---- untangle to amp^2 straight into registers (bins 0..256) ----
    double av[5];
    int    binv[5];
    #pragma unroll
    for (int u = 0; u < 4; ++u) {
        const int k = lane + 64 * u;
        const double2 zk = Zw[PAD8(k)];
        const double2 zm = Zw[PAD8((256 - k) & 255)];
        const double gr = 0.5 * (zk.x + zm.x);
        const double gi = 0.5 * (zk.y - zm.y);
        const double hr = 0.5 * (zk.y + zm.y);
        const double hi = 0.5 * (zm.x - zk.x);
        const double2 wv = W[k];
        const double xr = gr + wv.x * hr - wv.y * hi;
        const double xi = gi + wv.x * hi + wv.y * hr;
        av[u]   = (k == 0) ? 0.0 : (xr * xr + xi * xi);
        binv[u] = k;
    }
    av[4]   = -1.0;
    binv[4] = 256;
    if (lane == 0) {
        const double2 z0 = Zw[PAD8(0)];
        const double nyq = z0.x - z0.y;
        av[4] = nyq * nyq;
    }

    // ---- top-4, fully in registers (smallest-index tie-break) ----
    double bv[KP];
    int    bi[KP];
    #pragma unroll
    for (int q = 0; q < KP; ++q) {
        double v  = av[0];
        int    vi = binv[0];
        #pragma unroll
        for (int j = 1; j < 5; ++j)
            if (av[j] > v) { v = av[j]; vi = binv[j]; }
        #pragma unroll
        for (int off = 32; off > 0; off >>= 1) {
            const double ov = __shfl_xor(v, off, 64);
            const int    oi = __shfl_xor(vi, off, 64);
            if (ov > v || (ov == v && oi < vi)) { v = ov; vi = oi; }
        }
        bv[q] = v; bi[q] = vi;
        #pragma unroll
        for (int j = 0; j < 5; ++j)
            if (binv[j] == vi) av[j] = -1.0;
    }

    const int s = s0 + w;
    if (lane < KP) {
        // sqrt only for winners: identical bits to sqrt-then-select
        double v = lane == 0 ? bv[0] : lane == 1 ? bv[1] : lane == 2 ? bv[2] : bv[3];
        out_a[(size_t)s * KP + lane] = (float)sqrt(v);
    }
    if (lane == 0)
        bins[s] = make_int4(bi[0], bi[1], bi[2], bi[3]);
}

// ---------------------------------------------------------------------------
// Kernel 2: pure f32 gather/store. 8 waves/block; wave w -> (seq = w>>1,
// k-pair = (w&1)*2). Low VGPR -> 4 blocks/CU = 32 waves/CU.
// ---------------------------------------------------------------------------
__global__ __launch_bounds__(512, 8) void gather_store_kernel(
    const float* __restrict__ x,
    const int4* __restrict__ bins,
    float* __restrict__ out_g,
    float* __restrict__ out_m)
{
    const int tid  = threadIdx.x;
    const int lane = tid & 63;
    const int w    = tid >> 6;          // 0..7
    const int s0   = blockIdx.x << 2;
    const int b    = s0 >> 7;
    const int n0   = s0 & (NCH - 1);

    __shared__ float seqf[4 * SEQP];

    // issue staging loads into registers first; latency hides under m-phase
    const int col = tid & 3;
    const int t0  = tid >> 2;           // 0..127
    const float* xb = x + (size_t)b * TLEN * NCH + n0 + col;
    const float stage0 = xb[(size_t)(t0      ) * NCH];
    const float stage1 = xb[(size_t)(t0 + 128) * NCH];
    const float stage2 = xb[(size_t)(t0 + 256) * NCH];
    const float stage3 = xb[(size_t)(t0 + 384) * NCH];

    const int ls = w >> 1;              // local seq 0..3
    const int kb = (w & 1) << 1;        // k base: 0 or 2
    const int s  = s0 + ls;
    const int4 bn = bins[s];

    const int pp   = (lane & 15) << 2;  // p offset 0..60 step 4
    const int crow = lane >> 4;         // 0..3

    float* og = out_g + (size_t)s * (KP * CMAXV * PMAXV);
    float* om = out_m + (size_t)s * (KP * CMAXV * PMAXV);
    const nfloat4 zero = (nfloat4)(0.f, 0.f, 0.f, 0.f);

    // ---- phase 1: mask stores (independent of x) ----
    #pragma unroll
    for (int kk = 0; kk < 2; ++kk) {
        const int k = kb + kk;
        int ki = (k == 0) ? bn.x : (k == 1) ? bn.y : (k == 2) ? bn.z : bn.w;
        if (ki < 1) ki = 1;
        int P = TLEN / ki;
        P = P < MINP ? MINP : (P > PMAXV ? PMAXV : P);
        const int cyc = TLEN / P;       // 8..32

        nfloat4 mrow;
        mrow.x = (pp     < P) ? 1.f : 0.f;
        mrow.y = (pp + 1 < P) ? 1.f : 0.f;
        mrow.z = (pp + 2 < P) ? 1.f : 0.f;
        mrow.w = (pp + 3 < P) ? 1.f : 0.f;

        float* omk = om + k * (CMAXV * PMAXV) + pp;
        #pragma unroll
        for (int c8 = 0; c8 < 8; ++c8) {
            const int c = crow + 4 * c8;     // 0..31
            __builtin_nontemporal_store(c < cyc ? mrow : zero,
                                        (nfloat4*)(omk + c * PMAXV));
        }
    }

    // ---- stage rows into LDS ----
    {
        float* sc = seqf + col * SEQP;
        sc[t0      ] = stage0;
        sc[t0 + 128] = stage1;
        sc[t0 + 256] = stage2;
        sc[t0 + 384] = stage3;
    }
    __syncthreads();

    const float* sf = seqf + ls * SEQP;

    // ---- phase 2: gathered stores ----
    #pragma unroll
    for (int kk = 0; kk < 2; ++kk) {
        const int k = kb + kk;
        int ki = (k == 0) ? bn.x : (k == 1) ? bn.y : (k == 2) ? bn.z : bn.w;
        if (ki < 1) ki = 1;
        int P = TLEN / ki;
        P = P < MINP ? MINP : (P > PMAXV ? PMAXV : P);
        const int cyc  = TLEN / P;
        const int base = TLEN - cyc * P;

        float* ogk = og + k * (CMAXV * PMAXV) + pp;
        #pragma unroll
        for (int c8 = 0; c8 < 8; ++c8) {
            const int c = crow + 4 * c8;
            nfloat4 g = zero;
            if (c < cyc) {
                const int idx = base + c * P + pp;   // in-bounds whenever p < P
                if (pp     < P) g.x = sf[idx];
                if (pp + 1 < P) g.y = sf[idx + 1];
                if (pp + 2 < P) g.z = sf[idx + 2];
                if (pp + 3 < P) g.w = sf[idx + 3];
            }
            __builtin_nontemporal_store(g, (nfloat4*)(ogk + c * PMAXV));
        }
    }
}

extern "C" void kernel_launch(void* const* d_in, const int* in_sizes, int n_in,
                              void* d_out, int out_size, void* d_ws, size_t ws_size,
                              hipStream_t stream) {
    const float* x = (const float*)d_in[0];
    float* out = (float*)d_out;
    float* og = out;              // gathered: [B,N,K,Cmax,Pmax]
    float* om = out + OUTG;       // mask:     same shape
    float* oa = om + OUTG;        // kamp:     [B,N,K]
    int4*  bins = (int4*)d_ws;    // 4096 * 16 B = 64 KB scratch

    fft_topk_kernel<<<dim3(NSEQ / 4), dim3(256), 0, stream>>>(x, oa, bins);
    gather_store_kernel<<<dim3(NSEQ / 4), dim3(512), 0, stream>>>(x, bins, og, om);
}

// Round 4
// 264.597 us; speedup vs baseline: 1.0806x; 1.0806x over previous
//
#include <hip/hip_runtime.h>
#include <math.h>

#define TLEN 512
#define NCH  128
#define KP   4
#define PMAXV 64
#define CMAXV 32
#define MINP 16
#define NSEQ 4096   // B*N = 32*128
#define OUTG ((size_t)NSEQ * KP * CMAXV * PMAXV)   // 33,554,432

// pad-per-8 for 16B (double2) LDS elements: breaks power-of-2 bank strides
#define PAD8(i) ((i) + ((i) >> 3))
#define ZP   290            // >= PAD8(255)+1 = 287
#define SEQP 520            // padded f32 sequence row

typedef float nfloat4 __attribute__((ext_vector_type(4)));

// ---------------------------------------------------------------------------
// R15 = R13 resubmitted again (two rounds of "container failed twice" with
// zero compile/pytest signal -> infra, not kernel; source audited: all LDS
// indices bounded, no data-dependent loops, no hang mechanism).
// Pre-committed fallback: if this fails again, next round submits the
// byte-identical R11 kernel to disambiguate infra vs source.
//
// Fused single-pass (R11 structure — R12's two-kernel split regressed
// 266.8 -> 285.9 us: it killed FFT/store-drain overlap and re-paid the
// strided x load).  Change vs R11: radix-2 -> radix-4 FFT.
//   - 4 stages instead of 8: half the dependent LDS round-trip latencies
//     and wave_barriers, ~45% less LDS traffic, same FP64 flop count.
//   - W table extended to 384 entries (W_512^k, k<384; entries 256..383 via
//     W^(256+k) = -W^k) to cover radix-4 exponents 3*j*128/Q <= 378.
//   - Input permutation: base-4 digit reversal (pair-swapped bit-reverse).
// Store phase identical to R11 (verified).  Top-k selection is robust to the
// changed FFT rounding (amplitude gaps >> double ulp for random data).
// ---------------------------------------------------------------------------
__global__ __launch_bounds__(256) void periodicity_kernel(
    const float* __restrict__ x,
    float* __restrict__ out_g,
    float* __restrict__ out_m,
    float* __restrict__ out_a)
{
    const int tid  = threadIdx.x;
    const int lane = tid & 63;
    const int w    = tid >> 6;          // wave id = local sequence id
    const int s0   = blockIdx.x << 2;   // first sequence of this block
    const int b    = s0 >> 7;           // all 4 seqs share b (4 | 128)
    const int n0   = s0 & (NCH - 1);    // multiple of 4

    __shared__ float   seqf[4 * SEQP];
    __shared__ double2 Z[4 * ZP];
    __shared__ double2 W[384];          // W_512^j, j=0..383

    // ---- cooperative load + in-block twiddle table ----
    {
        const int col = tid & 3;
        const int t0  = tid >> 2;       // 0..63
        const float* base = x + (size_t)b * TLEN * NCH + n0 + col;
        #pragma unroll
        for (int it = 0; it < 8; ++it) {
            const int t = t0 + 64 * it;
            seqf[col * SEQP + t] = base[(size_t)t * NCH];
        }
        double ang = -6.283185307179586476925286766559 * (double)tid / (double)TLEN;
        double sv, cv;
        sincos(ang, &sv, &cv);
        W[tid] = make_double2(cv, sv);
        if (tid < 128)                       // W_512^(256+k) = -W_512^k
            W[256 + tid] = make_double2(-cv, -sv);
    }
    __syncthreads();                    // the ONLY block barrier

    float*   sf = seqf + w * SEQP;
    double2* Zw = Z + w * ZP;

    // ---- pack z[t]=x[2t]+i*x[2t+1], base-4 digit-reversed, 4 pts/lane ----
    #pragma unroll
    for (int u = 0; u < 4; ++u) {
        const int i = lane + 64 * u;
        const int rb = (int)(__brev((unsigned)i) >> 24);          // 8-bit reverse
        const int r  = ((rb >> 1) & 0x55) | ((rb & 0x55) << 1);   // pair swap -> base-4 digit reverse
        const float2 p = ((const float2*)sf)[r];                  // x[2r], x[2r+1]
        Zw[PAD8(i)] = make_double2((double)p.x, (double)p.y);
    }
    __builtin_amdgcn_wave_barrier();

    // ---- 4 radix-4 DIT stages over 256 complex pts (1 butterfly/lane) ----
    #pragma unroll
    for (int s4 = 0; s4 < 4; ++s4) {
        const int Q = 1 << (2 * s4);                  // 1,4,16,64
        const int j = lane & (Q - 1);
        const int o = ((lane >> (2 * s4)) << (2 * s4 + 2)) + j;   // A index

        double2 A  = Zw[PAD8(o)];
        double2 Bv = Zw[PAD8(o + Q)];
        double2 Cv = Zw[PAD8(o + 2 * Q)];
        double2 Dv = Zw[PAD8(o + 3 * Q)];

        if (s4 > 0) {
            const int t = j * (128 >> (2 * s4));      // j * 128/Q
            const double2 w1 = W[t];
            const double2 w2 = W[2 * t];
            const double2 w3 = W[3 * t];
            double br = Bv.x * w1.x - Bv.y * w1.y;
            double bi = Bv.x * w1.y + Bv.y * w1.x;
            Bv = make_double2(br, bi);
            double cr = Cv.x * w2.x - Cv.y * w2.y;
            double ci = Cv.x * w2.y + Cv.y * w2.x;
            Cv = make_double2(cr, ci);
            double dr = Dv.x * w3.x - Dv.y * w3.y;
            double di = Dv.x * w3.y + Dv.y * w3.x;
            Dv = make_double2(dr, di);
        }

        const double t0r = A.x + Cv.x, t0i = A.y + Cv.y;
        const double t1r = A.x - Cv.x, t1i = A.y - Cv.y;
        const double t2r = Bv.x + Dv.x, t2i = Bv.y + Dv.y;
        const double t3r = Bv.x - Dv.x, t3i = Bv.y - Dv.y;

        Zw[PAD8(o)]         = make_double2(t0r + t2r, t0i + t2i);  // t0 + t2
        Zw[PAD8(o + Q)]     = make_double2(t1r + t3i, t1i - t3r);  // t1 - i*t3
        Zw[PAD8(o + 2 * Q)] = make_double2(t0r - t2r, t0i - t2i);  // t0 - t2
        Zw[PAD8(o + 3 * Q)] = make_double2(t1r - t3i, t1i + t3r);  // t1 + i*t3
        __builtin_amdgcn_wave_barrier();
    }

    // ---- untangle to amp^2 straight into registers (bins 0..256) ----
    // E[k]=(Z[k]+conj(Z[256-k]))/2, O[k]=-i(Z[k]-conj(Z[256-k]))/2,
    // X[k]=E[k]+W_512^k*O[k];  X[256]=Re(Z0)-Im(Z0).
    double av[5];
    int    bins[5];
    #pragma unroll
    for (int u = 0; u < 4; ++u) {
        const int k = lane + 64 * u;
        const double2 zk = Zw[PAD8(k)];
        const double2 zm = Zw[PAD8((256 - k) & 255)];
        const double gr = 0.5 * (zk.x + zm.x);
        const double gi = 0.5 * (zk.y - zm.y);
        const double hr = 0.5 * (zk.y + zm.y);
        const double hi = 0.5 * (zm.x - zk.x);
        const double2 wv = W[k];
        const double xr = gr + wv.x * hr - wv.y * hi;
        const double xi = gi + wv.x * hi + wv.y * hr;
        av[u]   = (k == 0) ? 0.0 : (xr * xr + xi * xi);
        bins[u] = k;
    }
    av[4]   = -1.0;
    bins[4] = 256;
    if (lane == 0) {
        const double2 z0 = Zw[PAD8(0)];
        const double nyq = z0.x - z0.y;
        av[4] = nyq * nyq;
    }

    // ---- top-4, fully in registers (smallest-index tie-break) ----
    double bv[KP];
    int    bi[KP];
    #pragma unroll
    for (int q = 0; q < KP; ++q) {
        double v  = av[0];
        int    vi = bins[0];
        #pragma unroll
        for (int j = 1; j < 5; ++j)
            if (av[j] > v) { v = av[j]; vi = bins[j]; }
        #pragma unroll
        for (int off = 32; off > 0; off >>= 1) {
            const double ov = __shfl_xor(v, off, 64);
            const int    oi = __shfl_xor(vi, off, 64);
            if (ov > v || (ov == v && oi < vi)) { v = ov; vi = oi; }
        }
        bv[q] = v; bi[q] = vi;
        #pragma unroll
        for (int j = 0; j < 5; ++j)
            if (bins[j] == vi) av[j] = -1.0;
    }

    const int s = s0 + w;
    if (lane < KP) {
        // sqrt only for winners: identical bits to sqrt-then-select
        double v = lane == 0 ? bv[0] : lane == 1 ? bv[1] : lane == 2 ? bv[2] : bv[3];
        out_a[(size_t)s * KP + lane] = (float)sqrt(v);
    }

    float* og = out_g + (size_t)s * (KP * CMAXV * PMAXV);
    float* om = out_m + (size_t)s * (KP * CMAXV * PMAXV);
    const int pp   = (lane & 15) << 2;     // p offset 0..60 step 4
    const int crow = lane >> 4;            // 0..3

    // ---- merged store loop, k hoisted (params + mask row once per k) ----
    #pragma unroll
    for (int k = 0; k < KP; ++k) {
        int ki = bi[k] < 1 ? 1 : bi[k];
        int P  = TLEN / ki;
        P = P < MINP ? MINP : (P > PMAXV ? PMAXV : P);
        const int cyc  = TLEN / P;         // 8..32
        const int base = TLEN - cyc * P;

        // mask row pattern — identical for every live row of this k
        nfloat4 mrow;
        mrow.x = (pp     < P) ? 1.f : 0.f;
        mrow.y = (pp + 1 < P) ? 1.f : 0.f;
        mrow.z = (pp + 2 < P) ? 1.f : 0.f;
        mrow.w = (pp + 3 < P) ? 1.f : 0.f;

        float* ogk = og + k * (CMAXV * PMAXV) + pp;
        float* omk = om + k * (CMAXV * PMAXV) + pp;

        #pragma unroll
        for (int c8 = 0; c8 < 8; ++c8) {
            const int c = crow + 4 * c8;   // 0..31
            const bool live = c < cyc;
            nfloat4 m = (nfloat4)(0.f, 0.f, 0.f, 0.f);
            nfloat4 g = (nfloat4)(0.f, 0.f, 0.f, 0.f);
            if (live) {
                m = mrow;
                const int idx = base + c * P + pp;   // in-bounds whenever p < P
                if (pp     < P) g.x = sf[idx];
                if (pp + 1 < P) g.y = sf[idx + 1];
                if (pp + 2 < P) g.z = sf[idx + 2];
                if (pp + 3 < P) g.w = sf[idx + 3];
            }
            *(nfloat4*)(omk + c * PMAXV) = m;
            *(nfloat4*)(ogk + c * PMAXV) = g;
        }
    }
}

extern "C" void kernel_launch(void* const* d_in, const int* in_sizes, int n_in,
                              void* d_out, int out_size, void* d_ws, size_t ws_size,
                              hipStream_t stream) {
    const float* x = (const float*)d_in[0];
    float* out = (float*)d_out;
    float* og = out;              // gathered: [B,N,K,Cmax,Pmax]
    float* om = out + OUTG;       // mask:     same shape
    float* oa = om + OUTG;        // kamp:     [B,N,K]

    periodicity_kernel<<<dim3(NSEQ / 4), dim3(256), 0, stream>>>(x, og, om, oa);
}